// Round 15
// baseline (236.706 us; speedup 1.0000x reference)
//
#include <hip/hip_runtime.h>
#include <math.h>

#define NROWS 1024
#define DCOLS 16384
#define NTOT  16777216
#define BINS  1000
#define NPAIR2 36   // 8*9/2 upper-triangle 128x128 tile pairs
#define KSPL2  16   // split-K ways (K=1024 per slice)

typedef short short8 __attribute__((ext_vector_type(8)));
typedef unsigned short ushort8 __attribute__((ext_vector_type(8)));
typedef float f32x4 __attribute__((ext_vector_type(4)));

#define GLOAD_LDS16(gp, lp) __builtin_amdgcn_global_load_lds( \
    (const __attribute__((address_space(1))) unsigned int*)(gp), \
    (__attribute__((address_space(3))) unsigned int*)(lp), 16, 0, 0)

// check-entry tables (128-wide slots): target row, col base, fpart slot
__device__ __constant__ int CHK_TR[12] = {1,17,33,49,  0,5,10,15,  128,149,170,191};
__device__ __constant__ int CHK_CB[12] = {0,0,0,0,     128,128,128,128,  0,0,0,0};
__device__ __constant__ int CHK_SL[12] = {0,0,0,0,     1,1,1,1,    0,0,0,0};

// ---------------- K0: fused per-row stats + bf16 hi/lo split (one x pass) ----------------
__global__ __launch_bounds__(256) void k_rowsplit(const float* __restrict__ x,
    unsigned short* __restrict__ phi, unsigned short* __restrict__ plo,
    double* __restrict__ rowsum, double* __restrict__ rowsumsq,
    double* __restrict__ rowmin, double* __restrict__ rowmax) {
  const int row = blockIdx.x, t = threadIdx.x;
  const size_t base = (size_t)row * DCOLS;
  double s = 0.0, s2 = 0.0;
  float mn = 3.4028235e38f, mx = -3.4028235e38f;
  #pragma unroll
  for (int i = 0; i < 8; ++i) {
    const size_t off = base + (size_t)i * 2048 + (size_t)t * 8;
    const float4 v0 = *(const float4*)(x + off);
    const float4 v1 = *(const float4*)(x + off + 4);
    const float vv[8] = {v0.x, v0.y, v0.z, v0.w, v1.x, v1.y, v1.z, v1.w};
    ushort8 h, lo;
    #pragma unroll
    for (int c = 0; c < 8; ++c) {
      unsigned ub = __float_as_uint(vv[c]);
      unsigned hb = (ub + 0x7FFFu + ((ub >> 16) & 1u)) >> 16;   // RNE bf16
      float hf = __uint_as_float(hb << 16);
      float r = vv[c] - hf;                                      // exact
      unsigned ur = __float_as_uint(r);
      unsigned lb = (ur + 0x7FFFu + ((ur >> 16) & 1u)) >> 16;   // RNE bf16
      h[c] = (unsigned short)hb; lo[c] = (unsigned short)lb;
      double dv = vv[c];
      s += dv; s2 += dv * dv;
      mn = fminf(mn, vv[c]); mx = fmaxf(mx, vv[c]);
    }
    *(ushort8*)(phi + off) = h;
    *(ushort8*)(plo + off) = lo;
  }
  #pragma unroll
  for (int off = 32; off > 0; off >>= 1) {
    s  += __shfl_down(s, off);
    s2 += __shfl_down(s2, off);
    mn = fminf(mn, __shfl_down(mn, off));
    mx = fmaxf(mx, __shfl_down(mx, off));
  }
  __shared__ double lsd[8];
  __shared__ float  lsf[8];
  const int lane = t & 63, w = t >> 6;
  if (lane == 0) { lsd[w] = s; lsd[4 + w] = s2; lsf[w] = mn; lsf[4 + w] = mx; }
  __syncthreads();
  if (t == 0) {
    rowsum[row]   = (lsd[0] + lsd[1]) + (lsd[2] + lsd[3]);
    rowsumsq[row] = (lsd[4] + lsd[5]) + (lsd[6] + lsd[7]);
    rowmin[row] = (double)fminf(fminf(lsf[0], lsf[1]), fminf(lsf[2], lsf[3]));
    rowmax[row] = (double)fmaxf(fmaxf(lsf[4], lsf[5]), fmaxf(lsf[6], lsf[7]));
  }
}

// ---------------- K1 (fallback path only): per-row stats without split ----------------
__global__ __launch_bounds__(256) void k_rowstats(const float* __restrict__ x,
    double* __restrict__ rowsum, double* __restrict__ rowsumsq,
    double* __restrict__ rowmin, double* __restrict__ rowmax) {
  const int row = blockIdx.x;
  const int t = threadIdx.x;
  const float4* xr = (const float4*)(x + (size_t)row * DCOLS);
  double s = 0.0, s2 = 0.0;
  float mn = 3.4028235e38f, mx = -3.4028235e38f;
  for (int j = t; j < DCOLS / 4; j += 256) {
    float4 v = xr[j];
    double a = v.x, b = v.y, c = v.z, d = v.w;
    s  += (a + b) + (c + d);
    s2 += (a * a + b * b) + (c * c + d * d);
    mn = fminf(mn, fminf(fminf(v.x, v.y), fminf(v.z, v.w)));
    mx = fmaxf(mx, fmaxf(fmaxf(v.x, v.y), fmaxf(v.z, v.w)));
  }
  #pragma unroll
  for (int off = 32; off > 0; off >>= 1) {
    s  += __shfl_down(s, off);
    s2 += __shfl_down(s2, off);
    mn = fminf(mn, __shfl_down(mn, off));
    mx = fmaxf(mx, __shfl_down(mx, off));
  }
  __shared__ double lsd[8];
  __shared__ float  lsf[8];
  const int lane = t & 63, w = t >> 6;
  if (lane == 0) { lsd[w] = s; lsd[4 + w] = s2; lsf[w] = mn; lsf[4 + w] = mx; }
  __syncthreads();
  if (t == 0) {
    rowsum[row]   = (lsd[0] + lsd[1]) + (lsd[2] + lsd[3]);
    rowsumsq[row] = (lsd[4] + lsd[5]) + (lsd[6] + lsd[7]);
    rowmin[row] = (double)fminf(fminf(lsf[0], lsf[1]), fminf(lsf[2], lsf[3]));
    rowmax[row] = (double)fmaxf(fmaxf(lsf[4], lsf[5]), fmaxf(lsf[6], lsf[7]));
  }
}

// ---------------- K2: global scalars (fp64 stats -> float32 np-style scalars) + bc zero ----------------
__global__ __launch_bounds__(256) void k_stats2(
    const double* __restrict__ rowsum, const double* __restrict__ rowsumsq,
    const double* __restrict__ rowmin, const double* __restrict__ rowmax,
    double* __restrict__ m, double* __restrict__ dn, float* __restrict__ fscal,
    float* __restrict__ flg, unsigned* __restrict__ bc) {
#pragma clang fp contract(off)
  const int t = threadIdx.x;
  for (int b = t; b < BINS; b += 256) bc[b] = 0;   // needed only by fallback hist
  double s = 0.0, s2 = 0.0, mn = 1e300, mx = -1e300;
  for (int r = t; r < NROWS; r += 256) {
    s += rowsum[r]; s2 += rowsumsq[r];
    mn = fmin(mn, rowmin[r]); mx = fmax(mx, rowmax[r]);
  }
  #pragma unroll
  for (int off = 32; off > 0; off >>= 1) {
    s  += __shfl_down(s, off);
    s2 += __shfl_down(s2, off);
    mn = fmin(mn, __shfl_down(mn, off));
    mx = fmax(mx, __shfl_down(mx, off));
  }
  __shared__ double lsd[16];
  const int lane = t & 63, w = t >> 6;
  if (lane == 0) { lsd[w] = s; lsd[4 + w] = s2; lsd[8 + w] = mn; lsd[12 + w] = mx; }
  __syncthreads();
  if (t == 0) {
    double S  = (lsd[0] + lsd[1]) + (lsd[2] + lsd[3]);
    double S2 = (lsd[4] + lsd[5]) + (lsd[6] + lsd[7]);
    double MN = fmin(fmin(lsd[8], lsd[9]), fmin(lsd[10], lsd[11]));
    double MX = fmax(fmax(lsd[12], lsd[13]), fmax(lsd[14], lsd[15]));
    const double N = 16777216.0;
    double mu  = S / N;
    double var = (S2 - S * S / N) / (N - 1.0);
    double sig = sqrt(var);
    float mu32 = (float)mu;
    float sg32 = (float)sig;
    float mnf  = (float)MN;
    float mxf  = (float)MX;
    float lof  = (mnf - mu32) / sg32;
    float hif  = (mxf - mu32) / sg32;
    float wf   = (hif - lof) / 1000.0f;
    fscal[0] = mu32;
    fscal[1] = sg32;
    fscal[2] = lof;
    fscal[3] = wf;
    fscal[4] = 16384.0f * wf;
    fscal[5] = 16777216.0f * wf;
    flg[0] = 0.0f;
  }
  __syncthreads();
  for (int r = t; r < NROWS; r += 256) {
    double rs = rowsum[r];
    m[r]  = rs / 16384.0;
    dn[r] = sqrt(rowsumsq[r] - rs * rs * (1.0 / 16384.0));
  }
}

// ---- K5a: split-K(16) MFMA Gram, 128x128 tiles, K-chunk 32, merged hi/lo rows.
// ---- XCD-bijective block swizzle: a pair's 16 K-slices co-locate on one XCD (L2 panel reuse).
__global__ __launch_bounds__(256, 2) void k_gramm_sk(
    const unsigned short* __restrict__ phi, const unsigned short* __restrict__ plo,
    float* __restrict__ Gs) {
  const int logical = (blockIdx.x & 7) * 72 + (blockIdx.x >> 3);  // 576%8==0: bijective
  const int pid = logical >> 4, ks = logical & 15;
  int bi = 0, rem = pid;
  while (rem >= 8 - bi) { rem -= 8 - bi; ++bi; }   // pid -> (bi, bj) on 8x8, bi<=bj
  const int bj = bi + rem;
  const bool diag = (bi == bj);
  __shared__ short As[128][64];              // 16 KB
  __shared__ short Bs[128][64];              // 16 KB
  const int t = threadIdx.x;
  const int w = t >> 6, l = t & 63;

  // staging: w0,w1 -> A rows 0-63/64-127; w2,w3 -> B. 8 instr x 8 rows x 8 parts.
  // lane l: row_local = q*8 + (l>>3), part p = l&7, g = p ^ (l>>3); src plane by g>=4.
  const bool isB = (w >= 2);
  const int rbase = (w & 1) * 64;
  const int prow0 = (isB ? bj : bi) * 128;
  short* lbase = (isB ? &Bs[0][0] : &As[0][0]) + rbase * 64;
  const bool skipStage = diag && isB;
  const int g = (l & 7) ^ (l >> 3);
  const unsigned short* pl = (g & 4) ? plo : phi;
  const unsigned short* gbase = pl
      + (size_t)(prow0 + rbase + (l >> 3)) * DCOLS + (g & 3) * 8;

  f32x4 acc[4][4];
  #pragma unroll
  for (int a = 0; a < 4; ++a)
    #pragma unroll
    for (int b = 0; b < 4; ++b) acc[a][b] = (f32x4){0.f, 0.f, 0.f, 0.f};

  const int wr = w >> 1, wc = w & 1;          // wave's 64x64 quadrant
  const short* BA = diag ? &As[0][0] : &Bs[0][0];
  const int kbeg = ks * 1024;
  const int kp = l >> 4;                      // fragment k-part 0..3

  for (int k0 = kbeg; k0 < kbeg + 1024; k0 += 32) {
    __syncthreads();                          // previous chunk fully consumed
    if (!skipStage) {
      #pragma unroll
      for (int q = 0; q < 8; ++q)
        GLOAD_LDS16(gbase + (size_t)q * 8 * DCOLS + k0, lbase + q * 512);
    }
    __syncthreads();                          // staging drained (vmcnt before barrier)
    short8 ah[4], al[4];
    #pragma unroll
    for (int as_ = 0; as_ < 4; ++as_) {
      const int arow = wr * 64 + as_ * 16 + (l & 15);
      const int r7 = arow & 7;
      ah[as_] = *(const short8*)&As[arow][(kp ^ r7) * 8];
      al[as_] = *(const short8*)&As[arow][((4 + kp) ^ r7) * 8];
    }
    #pragma unroll
    for (int bs_ = 0; bs_ < 4; ++bs_) {
      const int brow = wc * 64 + bs_ * 16 + (l & 15);
      const int r7 = brow & 7;
      short8 bh = *(const short8*)(BA + brow * 64 + (kp ^ r7) * 8);
      short8 bl = *(const short8*)(BA + brow * 64 + ((4 + kp) ^ r7) * 8);
      #pragma unroll
      for (int as_ = 0; as_ < 4; ++as_) {
        acc[as_][bs_] = __builtin_amdgcn_mfma_f32_16x16x32_bf16(ah[as_], bh, acc[as_][bs_], 0, 0, 0);
        acc[as_][bs_] = __builtin_amdgcn_mfma_f32_16x16x32_bf16(ah[as_], bl, acc[as_][bs_], 0, 0, 0);
        acc[as_][bs_] = __builtin_amdgcn_mfma_f32_16x16x32_bf16(al[as_], bh, acc[as_][bs_], 0, 0, 0);
      }
    }
  }

  // write fp32 slice (16384 floats). C/D layout: col = lane&15, row = (lane>>4)*4+v
  float* gt = Gs + ((size_t)pid * KSPL2 + ks) * 16384;
  #pragma unroll
  for (int as_ = 0; as_ < 4; ++as_)
    #pragma unroll
    for (int bs_ = 0; bs_ < 4; ++bs_)
      #pragma unroll
      for (int v = 0; v < 4; ++v)
        gt[(wr * 64 + as_ * 16 + (l >> 4) * 4 + v) * 128 + wc * 64 + bs_ * 16 + (l & 15)]
            = acc[as_][bs_][v];
}

// ---- K5e: per-pair epilogue (blocks 0..nGepi-1) + spot-check partials (last 192) ----
__global__ __launch_bounds__(256) void k_gepi_chk(const float* __restrict__ x,
    const float* __restrict__ Gs, const double* __restrict__ m,
    const double* __restrict__ dn, double* __restrict__ fpart,
    double* __restrict__ chkpart, int nGepi) {
  const int t = threadIdx.x;
  if ((int)blockIdx.x >= nGepi) {
    // ---- spot-check partial: entry e (12) x col-group grp (16 of 8 cols) ----
    const int b = blockIdx.x - nGepi;
    const int e = b >> 4, grp = b & 15;
    const int cl = t >> 5;            // 0..7: col within group
    const int ksg = t & 31;           // 0..31: k segment (512 elems)
    const int trow = CHK_TR[e];
    const int col  = CHK_CB[e] + grp * 8 + cl;
    const float4* xa = (const float4*)(x + (size_t)trow * DCOLS) + ksg * 128;
    const float4* xb = (const float4*)(x + (size_t)col  * DCOLS) + ksg * 128;
    double g = 0.0;
    for (int k = 0; k < 128; ++k) {
      float4 va = xa[k], vb = xb[k];
      g += (double)va.x * vb.x + (double)va.y * vb.y
         + (double)va.z * vb.z + (double)va.w * vb.w;
    }
    g += __shfl_xor(g, 1); g += __shfl_xor(g, 2); g += __shfl_xor(g, 4);
    g += __shfl_xor(g, 8); g += __shfl_xor(g, 16);
    __shared__ double cd[8];
    if (ksg == 0) cd[cl] = g;
    __syncthreads();
    if (t == 0) {
      double s = 0.0;
      #pragma unroll
      for (int i = 0; i < 8; ++i) {
        int c = CHK_CB[e] + grp * 8 + i;
        double cov = cd[i] - 16384.0 * m[trow] * m[c];
        s += fabs(cov) / dn[c];
      }
      chkpart[e * 16 + grp] = s;
    }
    return;
  }
  // ---- gepi: 128x128 tile, processed in two 64-row halves ----
  const int pid = blockIdx.x;
  int bi = 0, rem = pid;
  while (rem >= 8 - bi) { rem -= 8 - bi; ++bi; }
  const int bj = bi + rem;
  const bool diag = (bi == bj);
  __shared__ double Gt[64][129];              // 64 rows x 128 cols, +1 pad
  const float* g = Gs + (size_t)pid * KSPL2 * 16384;
  double myScol = 0.0;                        // col-dir accumulator (owner: even t)
  const int cc = t >> 1, cq = t & 1;          // col c=t>>1, row-half q
  for (int h = 0; h < 2; ++h) {
    for (int i = t; i < 8192; i += 256) {
      const int off = h * 8192 + i;
      double sg = ((((double)g[off] + (double)g[16384 + off])
                 +  ((double)g[32768 + off] + (double)g[49152 + off]))
                +  (((double)g[65536 + off] + (double)g[81920 + off])
                 +  ((double)g[98304 + off] + (double)g[114688 + off])))
                + ((((double)g[131072 + off] + (double)g[147456 + off])
                 +  ((double)g[163840 + off] + (double)g[180224 + off]))
                +  (((double)g[196608 + off] + (double)g[212992 + off])
                 +  ((double)g[229376 + off] + (double)g[245760 + off])));
      Gt[i >> 7][i & 127] = sg;
    }
    __syncthreads();
    // row-direction: r = t>>2 (0..63), q = t&3 covers 32 cols
    {
      const int r = t >> 2, q = t & 3;
      const int grow = bi * 128 + h * 64 + r;
      const double mi = m[grow] * 16384.0;
      double s = 0.0;
      for (int i = 0; i < 32; ++i) {
        const int c = q * 32 + i;
        double cov = Gt[r][c] - mi * m[bj * 128 + c];
        s += fabs(cov) / dn[bj * 128 + c];
      }
      s += __shfl_xor(s, 1); s += __shfl_xor(s, 2);
      if (q == 0) fpart[(size_t)grow * 8 + bj] = s;
    }
    // col-direction (off-diag): c = t>>1, q = t&1 covers 32 rows of this half
    if (!diag) {
      const double mj = m[bj * 128 + cc] * 16384.0;
      double sc = 0.0;
      for (int i = 0; i < 32; ++i) {
        const int r = cq * 32 + i;
        const int grow = bi * 128 + h * 64 + r;
        double cov = Gt[r][cc] - m[grow] * mj;
        sc += fabs(cov) / dn[grow];
      }
      sc += __shfl_xor(sc, 1);
      if (cq == 0) myScol += sc;
    }
    __syncthreads();   // Gt reads done before next half overwrites
  }
  if (!diag && cq == 0)
    fpart[(size_t)(bj * 128 + cc) * 8 + bi] = myScol;
}

// ---------------- K5b: fallback fp32-VALU Gram (small ws; 16-slot fpart) ----------------
__global__ __launch_bounds__(256) void k_gram(const float* __restrict__ x,
    const double* __restrict__ m, const double* __restrict__ dn,
    double* __restrict__ fpart) {
  __shared__ float As[32][72];
  __shared__ float Bs[32][72];
  __shared__ double red[64][16];
  const int t = threadIdx.x;
  const int bi = blockIdx.y, bj = blockIdx.x;
  const int tx = t & 15, ty = t >> 4;
  const int lr = t >> 2, lc = t & 3;
  const float* Ap = x + (size_t)(bi * 64 + lr) * DCOLS;
  const float* Bp = x + (size_t)(bj * 64 + lr) * DCOLS;
  double acc[4][4];
  #pragma unroll
  for (int i = 0; i < 4; ++i)
    #pragma unroll
    for (int j = 0; j < 4; ++j) acc[i][j] = 0.0;
  float4 a0 = ((const float4*)Ap)[lc];
  float4 a1 = ((const float4*)Ap)[lc + 4];
  float4 b0 = ((const float4*)Bp)[lc];
  float4 b1 = ((const float4*)Bp)[lc + 4];
  for (int k0 = 0; k0 < DCOLS; k0 += 32) {
    __syncthreads();
    {
      const float* a0p = (const float*)&a0;
      const float* a1p = (const float*)&a1;
      const float* b0p = (const float*)&b0;
      const float* b1p = (const float*)&b1;
      #pragma unroll
      for (int jj = 0; jj < 4; ++jj) {
        As[lc * 4 + jj][lr]      = a0p[jj];
        As[16 + lc * 4 + jj][lr] = a1p[jj];
        Bs[lc * 4 + jj][lr]      = b0p[jj];
        Bs[16 + lc * 4 + jj][lr] = b1p[jj];
      }
    }
    __syncthreads();
    if (k0 + 32 < DCOLS) {
      a0 = ((const float4*)(Ap + k0 + 32))[lc];
      a1 = ((const float4*)(Ap + k0 + 32))[lc + 4];
      b0 = ((const float4*)(Bp + k0 + 32))[lc];
      b1 = ((const float4*)(Bp + k0 + 32))[lc + 4];
    }
    float ac[4][4];
    #pragma unroll
    for (int i = 0; i < 4; ++i)
      #pragma unroll
      for (int j = 0; j < 4; ++j) ac[i][j] = 0.0f;
    #pragma unroll
    for (int k = 0; k < 32; ++k) {
      const float4 av = *(const float4*)&As[k][ty * 4];
      const float4 bv = *(const float4*)&Bs[k][tx * 4];
      const float aa[4] = {av.x, av.y, av.z, av.w};
      const float bb[4] = {bv.x, bv.y, bv.z, bv.w};
      #pragma unroll
      for (int i = 0; i < 4; ++i)
        #pragma unroll
        for (int j = 0; j < 4; ++j)
          ac[i][j] += aa[i] * bb[j];
    }
    #pragma unroll
    for (int i = 0; i < 4; ++i)
      #pragma unroll
      for (int j = 0; j < 4; ++j) acc[i][j] += (double)ac[i][j];
  }
  double mr[4], mc[4], dc[4];
  #pragma unroll
  for (int i = 0; i < 4; ++i) mr[i] = m[bi * 64 + ty * 4 + i];
  #pragma unroll
  for (int j = 0; j < 4; ++j) {
    int col = bj * 64 + tx * 4 + j;
    mc[j] = m[col]; dc[j] = dn[col];
  }
  #pragma unroll
  for (int i = 0; i < 4; ++i) {
    double pi = 0.0;
    #pragma unroll
    for (int j = 0; j < 4; ++j) {
      double cov = acc[i][j] - 16384.0 * mr[i] * mc[j];
      pi += fabs(cov) / dc[j];
    }
    red[ty * 4 + i][tx] = pi;
  }
  __syncthreads();
  if (t < 64) {
    double ssum = 0.0;
    #pragma unroll
    for (int q = 0; q < 16; ++q) ssum += red[t][q];
    fpart[(size_t)(bi * 64 + t) * 16 + bj] = ssum;
  }
}

// ---- K3a (big path): per-row histogram, NO global atomics — writes rowcnt[row][1000] ----
__global__ __launch_bounds__(256) void k_hist_nc(const float* __restrict__ x,
    const float* __restrict__ fscal, double* __restrict__ localent,
    unsigned* __restrict__ rowcnt) {
#pragma clang fp contract(off)
  __shared__ unsigned h[4][BINS];
  const int row = blockIdx.x, t = threadIdx.x;
  const int w = t >> 6, lane = t & 63;
  for (int b = t; b < 4 * BINS; b += 256) h[b / BINS][b % BINS] = 0;
  __syncthreads();
  const float mu32 = fscal[0], sg32 = fscal[1], lof = fscal[2], wf = fscal[3];
  const float4* xr = (const float4*)(x + (size_t)row * DCOLS);
  for (int j = t; j < DCOLS / 4; j += 256) {
    float4 v = xr[j];
    float vv[4] = {v.x, v.y, v.z, v.w};
    #pragma unroll
    for (int c = 0; c < 4; ++c) {
      float tn = (vv[c] - mu32) / sg32;
      float q  = (tn - lof) / wf;
      int idx = (int)floorf(q);
      idx = idx < 0 ? 0 : (idx > BINS - 1 ? BINS - 1 : idx);
      atomicAdd(&h[w][idx], 1u);
    }
  }
  __syncthreads();
  const double Dw = (double)fscal[4];
  double ls = 0.0;
  for (int b = t; b < BINS; b += 256) {
    unsigned c = (h[0][b] + h[1][b]) + (h[2][b] + h[3][b]);
    rowcnt[(size_t)row * BINS + b] = c;      // plain coalesced store
    if (c) {
      double pd = (double)c / Dw;
      ls -= pd * log2(pd);
    }
  }
  #pragma unroll
  for (int off = 32; off > 0; off >>= 1) ls += __shfl_down(ls, off);
  __shared__ double lsd[4];
  if (lane == 0) lsd[w] = ls;
  __syncthreads();
  if (t == 0) localent[row] = (lsd[0] + lsd[1]) + (lsd[2] + lsd[3]);
}

// ---- K3c: batch counts = column sums of rowcnt (integer-exact). 125 blocks x 8 bins ----
__global__ __launch_bounds__(256) void k_bsum(const unsigned* __restrict__ rowcnt,
    unsigned* __restrict__ bc) {
  const int b0 = blockIdx.x * 8;
  const int t = threadIdx.x;
  unsigned ps[8] = {0, 0, 0, 0, 0, 0, 0, 0};
  for (int r = t; r < NROWS; r += 256) {
    const unsigned* rp = rowcnt + (size_t)r * BINS + b0;
    #pragma unroll
    for (int i = 0; i < 8; ++i) ps[i] += rp[i];
  }
  #pragma unroll
  for (int off = 32; off > 0; off >>= 1)
    #pragma unroll
    for (int i = 0; i < 8; ++i) ps[i] += __shfl_down(ps[i], off);
  __shared__ unsigned red[4][8];
  const int w = t >> 6, lane = t & 63;
  if (lane == 0) {
    #pragma unroll
    for (int i = 0; i < 8; ++i) red[w][i] = ps[i];
  }
  __syncthreads();
  if (t < 8)
    bc[b0 + t] = (red[0][t] + red[1][t]) + (red[2][t] + red[3][t]);
}

// ---- K3b (fallback): per-row histogram with global atomics (original) ----
__global__ __launch_bounds__(256) void k_hist(const float* __restrict__ x,
    const float* __restrict__ fscal, double* __restrict__ localent,
    unsigned* __restrict__ bc) {
#pragma clang fp contract(off)
  __shared__ unsigned h[4][BINS];
  const int row = blockIdx.x, t = threadIdx.x;
  const int w = t >> 6, lane = t & 63;
  for (int b = t; b < 4 * BINS; b += 256) h[b / BINS][b % BINS] = 0;
  __syncthreads();
  const float mu32 = fscal[0], sg32 = fscal[1], lof = fscal[2], wf = fscal[3];
  const float4* xr = (const float4*)(x + (size_t)row * DCOLS);
  for (int j = t; j < DCOLS / 4; j += 256) {
    float4 v = xr[j];
    float vv[4] = {v.x, v.y, v.z, v.w};
    #pragma unroll
    for (int c = 0; c < 4; ++c) {
      float tn = (vv[c] - mu32) / sg32;
      float q  = (tn - lof) / wf;
      int idx = (int)floorf(q);
      idx = idx < 0 ? 0 : (idx > BINS - 1 ? BINS - 1 : idx);
      atomicAdd(&h[w][idx], 1u);
    }
  }
  __syncthreads();
  const double Dw = (double)fscal[4];
  double ls = 0.0;
  for (int b = t; b < BINS; b += 256) {
    unsigned c = (h[0][b] + h[1][b]) + (h[2][b] + h[3][b]);
    if (c) {
      atomicAdd(&bc[b], c);
      double pd = (double)c / Dw;
      ls -= pd * log2(pd);
    }
  }
  #pragma unroll
  for (int off = 32; off > 0; off >>= 1) ls += __shfl_down(ls, off);
  __shared__ double lsd[4];
  if (lane == 0) lsd[w] = ls;
  __syncthreads();
  if (t == 0) localent[row] = (lsd[0] + lsd[1]) + (lsd[2] + lsd[3]);
}

// ---------------- K4: batch entropy + per-row pf/keepf + fpart spot-check compare ----------------
__global__ __launch_bounds__(256) void k_final(const unsigned* __restrict__ bc,
    const float* __restrict__ fscal, const double* __restrict__ localent,
    const double* __restrict__ fpart, const double* __restrict__ dn,
    const double* __restrict__ chkpart, float* __restrict__ flg,
    float* __restrict__ pf, float* __restrict__ kf, int nq, int doChk) {
#pragma clang fp contract(off)
  const int t = threadIdx.x;
  if (doChk && t < 12) {   // compare spot-check entries vs fpart
    double s = 0.0;
    #pragma unroll
    for (int q = 0; q < 16; ++q) s += chkpart[t * 16 + q];
    double got = fpart[(size_t)CHK_TR[t] * 8 + CHK_SL[t]];
    if (fabs(got - s) > 2e-3 * fmax(fabs(s), 1e-30))
      atomicAdd(flg, 1e6f * (float)(t + 1));
  }
  const double Nw = (double)fscal[5];
  double be = 0.0;
  for (int b = t; b < BINS; b += 256) {
    unsigned c = bc[b];
    if (c) { double pd = (double)c / Nw; be -= pd * log2(pd); }
  }
  #pragma unroll
  for (int off = 32; off > 0; off >>= 1) be += __shfl_down(be, off);
  __shared__ double lsd[4];
  __shared__ double sbent;
  const int lane = t & 63, w = t >> 6;
  if (lane == 0) lsd[w] = be;
  __syncthreads();
  if (t == 0) sbent = (lsd[0] + lsd[1]) + (lsd[2] + lsd[3]);
  __syncthreads();
  const float bef = (float)sbent;
  for (int r = t; r < NROWS; r += 256) {
    double s = 0.0;
    for (int q = 0; q < nq; ++q) s += fpart[(size_t)r * nq + q];
    float f1f = (float)(s / (dn[r] * 1024.0));
    float lef = (float)localent[r];
    float f2f = lef / bef;
    if (f2f == 0.0f) { f1f = 0.0f; f2f = 1.0f; }
    else if (f2f < 1.0f) f2f = 1.0f / f2f;
    float keepf = f1f / f2f;
    pf[r] = 1.0f - keepf;
    kf[r] = keepf;
  }
}

// ---------------- K6: elementwise masked scale (float32 compare + division) ----------------
__global__ __launch_bounds__(256) void k_apply(const float* __restrict__ x,
    const float* __restrict__ u, const float* __restrict__ pf,
    const float* __restrict__ kf, const float* __restrict__ flg,
    float* __restrict__ out) {
#pragma clang fp contract(off)
  const size_t e = ((size_t)blockIdx.x * 256 + threadIdx.x) * 4;
  const float fl = flg[0];
  if (fl != 0.0f) {           // diagnostic mode: encode check code in out[0]
    float4 o = {0.f, 0.f, 0.f, 0.f};
    if (e == 0) o.x = fl;
    *(float4*)(out + e) = o;
    return;
  }
  const int row = (int)(e >> 14);
  const float pr = pf[row], kr = kf[row];
  const float4 xv = *(const float4*)(x + e);
  const float4 uv = *(const float4*)(u + e);
  float4 o;
  o.x = (uv.x > pr) ? (xv.x / kr) : 0.0f;
  o.y = (uv.y > pr) ? (xv.y / kr) : 0.0f;
  o.z = (uv.z > pr) ? (xv.z / kr) : 0.0f;
  o.w = (uv.w > pr) ? (xv.w / kr) : 0.0f;
  *(float4*)(out + e) = o;
}

extern "C" void kernel_launch(void* const* d_in, const int* in_sizes, int n_in,
                              void* d_out, int out_size, void* d_ws, size_t ws_size,
                              hipStream_t stream) {
  const float* x = (const float*)d_in[0];
  const float* u = (const float*)d_in[1];
  float* out = (float*)d_out;

  const size_t PLANE = (size_t)NROWS * DCOLS * sizeof(unsigned short);  // 32 MB
  const size_t NDBL  = 7 * 1024 + (size_t)NROWS * 16 + 192;             // stats + fpart + chkpart
  const size_t TAILB = NDBL * 8 + (2056 + 4) * 4 + BINS * 4;
  const bool big = ws_size >= 2 * PLANE + TAILB;

  char* base = (char*)d_ws;
  unsigned short* phi = (unsigned short*)base;
  unsigned short* plo = (unsigned short*)(base + PLANE);
  double* W = big ? (double*)(base + 2 * PLANE) : (double*)base;

  double* rowsum   = W;
  double* rowsumsq = W + 1024;
  double* rowmin   = W + 2048;
  double* rowmax   = W + 3072;
  double* m        = W + 4096;
  double* dn       = W + 5120;
  double* localent = W + 6144;
  double* fpart    = W + 7168;                        // 1024*16 doubles (big uses stride 8)
  double* chkpart  = W + 7168 + (size_t)NROWS * 16;   // 192 doubles
  float*  F        = (float*)(chkpart + 192);
  float*  pf       = F;
  float*  kf       = F + 1024;
  float*  fscal    = F + 2048;          // 8 floats
  float*  flg      = F + 2056;          // 4 floats
  unsigned* bc     = (unsigned*)(F + 2060);

  if (big) {
    float* Gs = out;                                   // 9.44M floats (0..37.7MB of out)
    unsigned* rowcnt = (unsigned*)(out + 10485760);    // 4MB at +40MB, disjoint from Gs
    k_rowsplit<<<NROWS, 256, 0, stream>>>(x, phi, plo, rowsum, rowsumsq, rowmin, rowmax);
    k_stats2<<<1, 256, 0, stream>>>(rowsum, rowsumsq, rowmin, rowmax, m, dn, fscal, flg, bc);
    k_gramm_sk<<<NPAIR2 * KSPL2, 256, 0, stream>>>(phi, plo, Gs);
    k_gepi_chk<<<NPAIR2 + 192, 256, 0, stream>>>(x, Gs, m, dn, fpart, chkpart, NPAIR2);
    k_hist_nc<<<NROWS, 256, 0, stream>>>(x, fscal, localent, rowcnt);
    k_bsum<<<BINS / 8, 256, 0, stream>>>(rowcnt, bc);
    k_final<<<1, 256, 0, stream>>>(bc, fscal, localent, fpart, dn, chkpart, flg, pf, kf, 8, 1);
  } else {
    k_rowstats<<<NROWS, 256, 0, stream>>>(x, rowsum, rowsumsq, rowmin, rowmax);
    k_stats2<<<1, 256, 0, stream>>>(rowsum, rowsumsq, rowmin, rowmax, m, dn, fscal, flg, bc);
    k_gram<<<dim3(16, 16), 256, 0, stream>>>(x, m, dn, fpart);
    k_hist<<<NROWS, 256, 0, stream>>>(x, fscal, localent, bc);
    k_final<<<1, 256, 0, stream>>>(bc, fscal, localent, fpart, dn, chkpart, flg, pf, kf, 16, 0);
  }
  k_apply<<<NTOT / (256 * 4), 256, 0, stream>>>(x, u, pf, kf, flg, out);
}

// Round 16
// 195.086 us; speedup vs baseline: 1.2133x; 1.2133x over previous
//
#include <hip/hip_runtime.h>
#include <math.h>

#define NROWS 1024
#define DCOLS 16384
#define NTOT  16777216
#define BINS  1000
#define NPAIR2 36   // 8*9/2 upper-triangle 128x128 tile pairs
#define KSPL2  16   // split-K ways (K=1024 per slice)

typedef short short8 __attribute__((ext_vector_type(8)));
typedef unsigned short ushort8 __attribute__((ext_vector_type(8)));
typedef float f32x4 __attribute__((ext_vector_type(4)));

#define GLOAD_LDS16(gp, lp) __builtin_amdgcn_global_load_lds( \
    (const __attribute__((address_space(1))) unsigned int*)(gp), \
    (__attribute__((address_space(3))) unsigned int*)(lp), 16, 0, 0)

// check-entry tables (128-wide slots): target row, col base, fpart slot
__device__ __constant__ int CHK_TR[12] = {1,17,33,49,  0,5,10,15,  128,149,170,191};
__device__ __constant__ int CHK_CB[12] = {0,0,0,0,     128,128,128,128,  0,0,0,0};
__device__ __constant__ int CHK_SL[12] = {0,0,0,0,     1,1,1,1,    0,0,0,0};

// ---------------- K0: fused per-row stats + bf16 hi/lo split (one x pass) ----------------
__global__ __launch_bounds__(256) void k_rowsplit(const float* __restrict__ x,
    unsigned short* __restrict__ phi, unsigned short* __restrict__ plo,
    double* __restrict__ rowsum, double* __restrict__ rowsumsq,
    double* __restrict__ rowmin, double* __restrict__ rowmax) {
  const int row = blockIdx.x, t = threadIdx.x;
  const size_t base = (size_t)row * DCOLS;
  double s = 0.0, s2 = 0.0;
  float mn = 3.4028235e38f, mx = -3.4028235e38f;
  #pragma unroll
  for (int i = 0; i < 8; ++i) {
    const size_t off = base + (size_t)i * 2048 + (size_t)t * 8;
    const float4 v0 = *(const float4*)(x + off);
    const float4 v1 = *(const float4*)(x + off + 4);
    const float vv[8] = {v0.x, v0.y, v0.z, v0.w, v1.x, v1.y, v1.z, v1.w};
    ushort8 h, lo;
    #pragma unroll
    for (int c = 0; c < 8; ++c) {
      unsigned ub = __float_as_uint(vv[c]);
      unsigned hb = (ub + 0x7FFFu + ((ub >> 16) & 1u)) >> 16;   // RNE bf16
      float hf = __uint_as_float(hb << 16);
      float r = vv[c] - hf;                                      // exact
      unsigned ur = __float_as_uint(r);
      unsigned lb = (ur + 0x7FFFu + ((ur >> 16) & 1u)) >> 16;   // RNE bf16
      h[c] = (unsigned short)hb; lo[c] = (unsigned short)lb;
      double dv = vv[c];
      s += dv; s2 += dv * dv;
      mn = fminf(mn, vv[c]); mx = fmaxf(mx, vv[c]);
    }
    *(ushort8*)(phi + off) = h;
    *(ushort8*)(plo + off) = lo;
  }
  #pragma unroll
  for (int off = 32; off > 0; off >>= 1) {
    s  += __shfl_down(s, off);
    s2 += __shfl_down(s2, off);
    mn = fminf(mn, __shfl_down(mn, off));
    mx = fmaxf(mx, __shfl_down(mx, off));
  }
  __shared__ double lsd[8];
  __shared__ float  lsf[8];
  const int lane = t & 63, w = t >> 6;
  if (lane == 0) { lsd[w] = s; lsd[4 + w] = s2; lsf[w] = mn; lsf[4 + w] = mx; }
  __syncthreads();
  if (t == 0) {
    rowsum[row]   = (lsd[0] + lsd[1]) + (lsd[2] + lsd[3]);
    rowsumsq[row] = (lsd[4] + lsd[5]) + (lsd[6] + lsd[7]);
    rowmin[row] = (double)fminf(fminf(lsf[0], lsf[1]), fminf(lsf[2], lsf[3]));
    rowmax[row] = (double)fmaxf(fmaxf(lsf[4], lsf[5]), fmaxf(lsf[6], lsf[7]));
  }
}

// ---------------- K1 (fallback path only): per-row stats without split ----------------
__global__ __launch_bounds__(256) void k_rowstats(const float* __restrict__ x,
    double* __restrict__ rowsum, double* __restrict__ rowsumsq,
    double* __restrict__ rowmin, double* __restrict__ rowmax) {
  const int row = blockIdx.x;
  const int t = threadIdx.x;
  const float4* xr = (const float4*)(x + (size_t)row * DCOLS);
  double s = 0.0, s2 = 0.0;
  float mn = 3.4028235e38f, mx = -3.4028235e38f;
  for (int j = t; j < DCOLS / 4; j += 256) {
    float4 v = xr[j];
    double a = v.x, b = v.y, c = v.z, d = v.w;
    s  += (a + b) + (c + d);
    s2 += (a * a + b * b) + (c * c + d * d);
    mn = fminf(mn, fminf(fminf(v.x, v.y), fminf(v.z, v.w)));
    mx = fmaxf(mx, fmaxf(fmaxf(v.x, v.y), fmaxf(v.z, v.w)));
  }
  #pragma unroll
  for (int off = 32; off > 0; off >>= 1) {
    s  += __shfl_down(s, off);
    s2 += __shfl_down(s2, off);
    mn = fminf(mn, __shfl_down(mn, off));
    mx = fmaxf(mx, __shfl_down(mx, off));
  }
  __shared__ double lsd[8];
  __shared__ float  lsf[8];
  const int lane = t & 63, w = t >> 6;
  if (lane == 0) { lsd[w] = s; lsd[4 + w] = s2; lsf[w] = mn; lsf[4 + w] = mx; }
  __syncthreads();
  if (t == 0) {
    rowsum[row]   = (lsd[0] + lsd[1]) + (lsd[2] + lsd[3]);
    rowsumsq[row] = (lsd[4] + lsd[5]) + (lsd[6] + lsd[7]);
    rowmin[row] = (double)fminf(fminf(lsf[0], lsf[1]), fminf(lsf[2], lsf[3]));
    rowmax[row] = (double)fmaxf(fmaxf(lsf[4], lsf[5]), fmaxf(lsf[6], lsf[7]));
  }
}

// ---------------- K2: global scalars (fp64 stats -> float32 np-style scalars) + bc zero ----------------
__global__ __launch_bounds__(256) void k_stats2(
    const double* __restrict__ rowsum, const double* __restrict__ rowsumsq,
    const double* __restrict__ rowmin, const double* __restrict__ rowmax,
    double* __restrict__ m, double* __restrict__ dn, float* __restrict__ fscal,
    float* __restrict__ flg, unsigned* __restrict__ bc) {
#pragma clang fp contract(off)
  const int t = threadIdx.x;
  for (int b = t; b < BINS; b += 256) bc[b] = 0;   // needed only by fallback hist
  double s = 0.0, s2 = 0.0, mn = 1e300, mx = -1e300;
  for (int r = t; r < NROWS; r += 256) {
    s += rowsum[r]; s2 += rowsumsq[r];
    mn = fmin(mn, rowmin[r]); mx = fmax(mx, rowmax[r]);
  }
  #pragma unroll
  for (int off = 32; off > 0; off >>= 1) {
    s  += __shfl_down(s, off);
    s2 += __shfl_down(s2, off);
    mn = fmin(mn, __shfl_down(mn, off));
    mx = fmax(mx, __shfl_down(mx, off));
  }
  __shared__ double lsd[16];
  const int lane = t & 63, w = t >> 6;
  if (lane == 0) { lsd[w] = s; lsd[4 + w] = s2; lsd[8 + w] = mn; lsd[12 + w] = mx; }
  __syncthreads();
  if (t == 0) {
    double S  = (lsd[0] + lsd[1]) + (lsd[2] + lsd[3]);
    double S2 = (lsd[4] + lsd[5]) + (lsd[6] + lsd[7]);
    double MN = fmin(fmin(lsd[8], lsd[9]), fmin(lsd[10], lsd[11]));
    double MX = fmax(fmax(lsd[12], lsd[13]), fmax(lsd[14], lsd[15]));
    const double N = 16777216.0;
    double mu  = S / N;
    double var = (S2 - S * S / N) / (N - 1.0);
    double sig = sqrt(var);
    float mu32 = (float)mu;
    float sg32 = (float)sig;
    float mnf  = (float)MN;
    float mxf  = (float)MX;
    float lof  = (mnf - mu32) / sg32;
    float hif  = (mxf - mu32) / sg32;
    float wf   = (hif - lof) / 1000.0f;
    fscal[0] = mu32;
    fscal[1] = sg32;
    fscal[2] = lof;
    fscal[3] = wf;
    fscal[4] = 16384.0f * wf;
    fscal[5] = 16777216.0f * wf;
    flg[0] = 0.0f;
  }
  __syncthreads();
  for (int r = t; r < NROWS; r += 256) {
    double rs = rowsum[r];
    m[r]  = rs / 16384.0;
    dn[r] = sqrt(rowsumsq[r] - rs * rs * (1.0 / 16384.0));
  }
}

// ---- K5a: split-K(16) MFMA Gram, 128x128 tiles, K-chunk 32, merged hi/lo rows.
// ---- Default block order (r15's XCD swizzle REVERTED: it 5x'd HBM fetch).
__global__ __launch_bounds__(256, 2) void k_gramm_sk(
    const unsigned short* __restrict__ phi, const unsigned short* __restrict__ plo,
    float* __restrict__ Gs) {
  const int pid = blockIdx.x >> 4, ks = blockIdx.x & 15;
  int bi = 0, rem = pid;
  while (rem >= 8 - bi) { rem -= 8 - bi; ++bi; }   // pid -> (bi, bj) on 8x8, bi<=bj
  const int bj = bi + rem;
  const bool diag = (bi == bj);
  __shared__ short As[128][64];              // 16 KB
  __shared__ short Bs[128][64];              // 16 KB
  const int t = threadIdx.x;
  const int w = t >> 6, l = t & 63;

  // staging: w0,w1 -> A rows 0-63/64-127; w2,w3 -> B. 8 instr x 8 rows x 8 parts.
  // lane l: row_local = q*8 + (l>>3), part p = l&7, g = p ^ (l>>3); src plane by g>=4.
  const bool isB = (w >= 2);
  const int rbase = (w & 1) * 64;
  const int prow0 = (isB ? bj : bi) * 128;
  short* lbase = (isB ? &Bs[0][0] : &As[0][0]) + rbase * 64;
  const bool skipStage = diag && isB;
  const int g = (l & 7) ^ (l >> 3);
  const unsigned short* pl = (g & 4) ? plo : phi;
  const unsigned short* gbase = pl
      + (size_t)(prow0 + rbase + (l >> 3)) * DCOLS + (g & 3) * 8;

  f32x4 acc[4][4];
  #pragma unroll
  for (int a = 0; a < 4; ++a)
    #pragma unroll
    for (int b = 0; b < 4; ++b) acc[a][b] = (f32x4){0.f, 0.f, 0.f, 0.f};

  const int wr = w >> 1, wc = w & 1;          // wave's 64x64 quadrant
  const short* BA = diag ? &As[0][0] : &Bs[0][0];
  const int kbeg = ks * 1024;
  const int kp = l >> 4;                      // fragment k-part 0..3

  for (int k0 = kbeg; k0 < kbeg + 1024; k0 += 32) {
    __syncthreads();                          // previous chunk fully consumed
    if (!skipStage) {
      #pragma unroll
      for (int q = 0; q < 8; ++q)
        GLOAD_LDS16(gbase + (size_t)q * 8 * DCOLS + k0, lbase + q * 512);
    }
    __syncthreads();                          // staging drained (vmcnt before barrier)
    short8 ah[4], al[4];
    #pragma unroll
    for (int as_ = 0; as_ < 4; ++as_) {
      const int arow = wr * 64 + as_ * 16 + (l & 15);
      const int r7 = arow & 7;
      ah[as_] = *(const short8*)&As[arow][(kp ^ r7) * 8];
      al[as_] = *(const short8*)&As[arow][((4 + kp) ^ r7) * 8];
    }
    #pragma unroll
    for (int bs_ = 0; bs_ < 4; ++bs_) {
      const int brow = wc * 64 + bs_ * 16 + (l & 15);
      const int r7 = brow & 7;
      short8 bh = *(const short8*)(BA + brow * 64 + (kp ^ r7) * 8);
      short8 bl = *(const short8*)(BA + brow * 64 + ((4 + kp) ^ r7) * 8);
      #pragma unroll
      for (int as_ = 0; as_ < 4; ++as_) {
        acc[as_][bs_] = __builtin_amdgcn_mfma_f32_16x16x32_bf16(ah[as_], bh, acc[as_][bs_], 0, 0, 0);
        acc[as_][bs_] = __builtin_amdgcn_mfma_f32_16x16x32_bf16(ah[as_], bl, acc[as_][bs_], 0, 0, 0);
        acc[as_][bs_] = __builtin_amdgcn_mfma_f32_16x16x32_bf16(al[as_], bh, acc[as_][bs_], 0, 0, 0);
      }
    }
  }

  // write fp32 slice (16384 floats). C/D layout: col = lane&15, row = (lane>>4)*4+v
  float* gt = Gs + ((size_t)pid * KSPL2 + ks) * 16384;
  #pragma unroll
  for (int as_ = 0; as_ < 4; ++as_)
    #pragma unroll
    for (int bs_ = 0; bs_ < 4; ++bs_)
      #pragma unroll
      for (int v = 0; v < 4; ++v)
        gt[(wr * 64 + as_ * 16 + (l >> 4) * 4 + v) * 128 + wc * 64 + bs_ * 16 + (l & 15)]
            = acc[as_][bs_][v];
}

// ---- K5e: per-pair epilogue (blocks 0..nGepi-1) + spot-check partials (last 192) ----
__global__ __launch_bounds__(256) void k_gepi_chk(const float* __restrict__ x,
    const float* __restrict__ Gs, const double* __restrict__ m,
    const double* __restrict__ dn, double* __restrict__ fpart,
    double* __restrict__ chkpart, int nGepi) {
  const int t = threadIdx.x;
  if ((int)blockIdx.x >= nGepi) {
    // ---- spot-check partial: entry e (12) x col-group grp (16 of 8 cols) ----
    const int b = blockIdx.x - nGepi;
    const int e = b >> 4, grp = b & 15;
    const int cl = t >> 5;            // 0..7: col within group
    const int ksg = t & 31;           // 0..31: k segment (512 elems)
    const int trow = CHK_TR[e];
    const int col  = CHK_CB[e] + grp * 8 + cl;
    const float4* xa = (const float4*)(x + (size_t)trow * DCOLS) + ksg * 128;
    const float4* xb = (const float4*)(x + (size_t)col  * DCOLS) + ksg * 128;
    double g = 0.0;
    for (int k = 0; k < 128; ++k) {
      float4 va = xa[k], vb = xb[k];
      g += (double)va.x * vb.x + (double)va.y * vb.y
         + (double)va.z * vb.z + (double)va.w * vb.w;
    }
    g += __shfl_xor(g, 1); g += __shfl_xor(g, 2); g += __shfl_xor(g, 4);
    g += __shfl_xor(g, 8); g += __shfl_xor(g, 16);
    __shared__ double cd[8];
    if (ksg == 0) cd[cl] = g;
    __syncthreads();
    if (t == 0) {
      double s = 0.0;
      #pragma unroll
      for (int i = 0; i < 8; ++i) {
        int c = CHK_CB[e] + grp * 8 + i;
        double cov = cd[i] - 16384.0 * m[trow] * m[c];
        s += fabs(cov) / dn[c];
      }
      chkpart[e * 16 + grp] = s;
    }
    return;
  }
  // ---- gepi: 128x128 tile, processed in two 64-row halves ----
  const int pid = blockIdx.x;
  int bi = 0, rem = pid;
  while (rem >= 8 - bi) { rem -= 8 - bi; ++bi; }
  const int bj = bi + rem;
  const bool diag = (bi == bj);
  __shared__ double Gt[64][129];              // 64 rows x 128 cols, +1 pad
  const float* g = Gs + (size_t)pid * KSPL2 * 16384;
  double myScol = 0.0;                        // col-dir accumulator (owner: even t)
  const int cc = t >> 1, cq = t & 1;          // col c=t>>1, row-half q
  for (int h = 0; h < 2; ++h) {
    for (int i = t; i < 8192; i += 256) {
      const int off = h * 8192 + i;
      double sg = ((((double)g[off] + (double)g[16384 + off])
                 +  ((double)g[32768 + off] + (double)g[49152 + off]))
                +  (((double)g[65536 + off] + (double)g[81920 + off])
                 +  ((double)g[98304 + off] + (double)g[114688 + off])))
                + ((((double)g[131072 + off] + (double)g[147456 + off])
                 +  ((double)g[163840 + off] + (double)g[180224 + off]))
                +  (((double)g[196608 + off] + (double)g[212992 + off])
                 +  ((double)g[229376 + off] + (double)g[245760 + off])));
      Gt[i >> 7][i & 127] = sg;
    }
    __syncthreads();
    // row-direction: r = t>>2 (0..63), q = t&3 covers 32 cols
    {
      const int r = t >> 2, q = t & 3;
      const int grow = bi * 128 + h * 64 + r;
      const double mi = m[grow] * 16384.0;
      double s = 0.0;
      for (int i = 0; i < 32; ++i) {
        const int c = q * 32 + i;
        double cov = Gt[r][c] - mi * m[bj * 128 + c];
        s += fabs(cov) / dn[bj * 128 + c];
      }
      s += __shfl_xor(s, 1); s += __shfl_xor(s, 2);
      if (q == 0) fpart[(size_t)grow * 8 + bj] = s;
    }
    // col-direction (off-diag): c = t>>1, q = t&1 covers 32 rows of this half
    if (!diag) {
      const double mj = m[bj * 128 + cc] * 16384.0;
      double sc = 0.0;
      for (int i = 0; i < 32; ++i) {
        const int r = cq * 32 + i;
        const int grow = bi * 128 + h * 64 + r;
        double cov = Gt[r][cc] - m[grow] * mj;
        sc += fabs(cov) / dn[grow];
      }
      sc += __shfl_xor(sc, 1);
      if (cq == 0) myScol += sc;
    }
    __syncthreads();   // Gt reads done before next half overwrites
  }
  if (!diag && cq == 0)
    fpart[(size_t)(bj * 128 + cc) * 8 + bi] = myScol;
}

// ---------------- K5b: fallback fp32-VALU Gram (small ws; 16-slot fpart) ----------------
__global__ __launch_bounds__(256) void k_gram(const float* __restrict__ x,
    const double* __restrict__ m, const double* __restrict__ dn,
    double* __restrict__ fpart) {
  __shared__ float As[32][72];
  __shared__ float Bs[32][72];
  __shared__ double red[64][16];
  const int t = threadIdx.x;
  const int bi = blockIdx.y, bj = blockIdx.x;
  const int tx = t & 15, ty = t >> 4;
  const int lr = t >> 2, lc = t & 3;
  const float* Ap = x + (size_t)(bi * 64 + lr) * DCOLS;
  const float* Bp = x + (size_t)(bj * 64 + lr) * DCOLS;
  double acc[4][4];
  #pragma unroll
  for (int i = 0; i < 4; ++i)
    #pragma unroll
    for (int j = 0; j < 4; ++j) acc[i][j] = 0.0;
  float4 a0 = ((const float4*)Ap)[lc];
  float4 a1 = ((const float4*)Ap)[lc + 4];
  float4 b0 = ((const float4*)Bp)[lc];
  float4 b1 = ((const float4*)Bp)[lc + 4];
  for (int k0 = 0; k0 < DCOLS; k0 += 32) {
    __syncthreads();
    {
      const float* a0p = (const float*)&a0;
      const float* a1p = (const float*)&a1;
      const float* b0p = (const float*)&b0;
      const float* b1p = (const float*)&b1;
      #pragma unroll
      for (int jj = 0; jj < 4; ++jj) {
        As[lc * 4 + jj][lr]      = a0p[jj];
        As[16 + lc * 4 + jj][lr] = a1p[jj];
        Bs[lc * 4 + jj][lr]      = b0p[jj];
        Bs[16 + lc * 4 + jj][lr] = b1p[jj];
      }
    }
    __syncthreads();
    if (k0 + 32 < DCOLS) {
      a0 = ((const float4*)(Ap + k0 + 32))[lc];
      a1 = ((const float4*)(Ap + k0 + 32))[lc + 4];
      b0 = ((const float4*)(Bp + k0 + 32))[lc];
      b1 = ((const float4*)(Bp + k0 + 32))[lc + 4];
    }
    float ac[4][4];
    #pragma unroll
    for (int i = 0; i < 4; ++i)
      #pragma unroll
      for (int j = 0; j < 4; ++j) ac[i][j] = 0.0f;
    #pragma unroll
    for (int k = 0; k < 32; ++k) {
      const float4 av = *(const float4*)&As[k][ty * 4];
      const float4 bv = *(const float4*)&Bs[k][tx * 4];
      const float aa[4] = {av.x, av.y, av.z, av.w};
      const float bb[4] = {bv.x, bv.y, bv.z, bv.w};
      #pragma unroll
      for (int i = 0; i < 4; ++i)
        #pragma unroll
        for (int j = 0; j < 4; ++j)
          ac[i][j] += aa[i] * bb[j];
    }
    #pragma unroll
    for (int i = 0; i < 4; ++i)
      #pragma unroll
      for (int j = 0; j < 4; ++j) acc[i][j] += (double)ac[i][j];
  }
  double mr[4], mc[4], dc[4];
  #pragma unroll
  for (int i = 0; i < 4; ++i) mr[i] = m[bi * 64 + ty * 4 + i];
  #pragma unroll
  for (int j = 0; j < 4; ++j) {
    int col = bj * 64 + tx * 4 + j;
    mc[j] = m[col]; dc[j] = dn[col];
  }
  #pragma unroll
  for (int i = 0; i < 4; ++i) {
    double pi = 0.0;
    #pragma unroll
    for (int j = 0; j < 4; ++j) {
      double cov = acc[i][j] - 16384.0 * mr[i] * mc[j];
      pi += fabs(cov) / dc[j];
    }
    red[ty * 4 + i][tx] = pi;
  }
  __syncthreads();
  if (t < 64) {
    double ssum = 0.0;
    #pragma unroll
    for (int q = 0; q < 16; ++q) ssum += red[t][q];
    fpart[(size_t)(bi * 64 + t) * 16 + bj] = ssum;
  }
}

// ---- K3a (big path): per-row histogram, NO global atomics — writes rowcnt[row][1000] ----
__global__ __launch_bounds__(256) void k_hist_nc(const float* __restrict__ x,
    const float* __restrict__ fscal, double* __restrict__ localent,
    unsigned* __restrict__ rowcnt) {
#pragma clang fp contract(off)
  __shared__ unsigned h[4][BINS];
  const int row = blockIdx.x, t = threadIdx.x;
  const int w = t >> 6, lane = t & 63;
  for (int b = t; b < 4 * BINS; b += 256) h[b / BINS][b % BINS] = 0;
  __syncthreads();
  const float mu32 = fscal[0], sg32 = fscal[1], lof = fscal[2], wf = fscal[3];
  const float4* xr = (const float4*)(x + (size_t)row * DCOLS);
  for (int j = t; j < DCOLS / 4; j += 256) {
    float4 v = xr[j];
    float vv[4] = {v.x, v.y, v.z, v.w};
    #pragma unroll
    for (int c = 0; c < 4; ++c) {
      float tn = (vv[c] - mu32) / sg32;
      float q  = (tn - lof) / wf;
      int idx = (int)floorf(q);
      idx = idx < 0 ? 0 : (idx > BINS - 1 ? BINS - 1 : idx);
      atomicAdd(&h[w][idx], 1u);
    }
  }
  __syncthreads();
  const double Dw = (double)fscal[4];
  double ls = 0.0;
  for (int b = t; b < BINS; b += 256) {
    unsigned c = (h[0][b] + h[1][b]) + (h[2][b] + h[3][b]);
    rowcnt[(size_t)row * BINS + b] = c;      // plain coalesced store
    if (c) {
      double pd = (double)c / Dw;
      ls -= pd * log2(pd);
    }
  }
  #pragma unroll
  for (int off = 32; off > 0; off >>= 1) ls += __shfl_down(ls, off);
  __shared__ double lsd[4];
  if (lane == 0) lsd[w] = ls;
  __syncthreads();
  if (t == 0) localent[row] = (lsd[0] + lsd[1]) + (lsd[2] + lsd[3]);
}

// ---- K3c: batch counts = column sums of rowcnt (integer-exact). 125 blocks x 8 bins ----
__global__ __launch_bounds__(256) void k_bsum(const unsigned* __restrict__ rowcnt,
    unsigned* __restrict__ bc) {
  const int b0 = blockIdx.x * 8;
  const int t = threadIdx.x;
  unsigned ps[8] = {0, 0, 0, 0, 0, 0, 0, 0};
  for (int r = t; r < NROWS; r += 256) {
    const unsigned* rp = rowcnt + (size_t)r * BINS + b0;
    #pragma unroll
    for (int i = 0; i < 8; ++i) ps[i] += rp[i];
  }
  #pragma unroll
  for (int off = 32; off > 0; off >>= 1)
    #pragma unroll
    for (int i = 0; i < 8; ++i) ps[i] += __shfl_down(ps[i], off);
  __shared__ unsigned red[4][8];
  const int w = t >> 6, lane = t & 63;
  if (lane == 0) {
    #pragma unroll
    for (int i = 0; i < 8; ++i) red[w][i] = ps[i];
  }
  __syncthreads();
  if (t < 8)
    bc[b0 + t] = (red[0][t] + red[1][t]) + (red[2][t] + red[3][t]);
}

// ---- K3b (fallback): per-row histogram with global atomics (original) ----
__global__ __launch_bounds__(256) void k_hist(const float* __restrict__ x,
    const float* __restrict__ fscal, double* __restrict__ localent,
    unsigned* __restrict__ bc) {
#pragma clang fp contract(off)
  __shared__ unsigned h[4][BINS];
  const int row = blockIdx.x, t = threadIdx.x;
  const int w = t >> 6, lane = t & 63;
  for (int b = t; b < 4 * BINS; b += 256) h[b / BINS][b % BINS] = 0;
  __syncthreads();
  const float mu32 = fscal[0], sg32 = fscal[1], lof = fscal[2], wf = fscal[3];
  const float4* xr = (const float4*)(x + (size_t)row * DCOLS);
  for (int j = t; j < DCOLS / 4; j += 256) {
    float4 v = xr[j];
    float vv[4] = {v.x, v.y, v.z, v.w};
    #pragma unroll
    for (int c = 0; c < 4; ++c) {
      float tn = (vv[c] - mu32) / sg32;
      float q  = (tn - lof) / wf;
      int idx = (int)floorf(q);
      idx = idx < 0 ? 0 : (idx > BINS - 1 ? BINS - 1 : idx);
      atomicAdd(&h[w][idx], 1u);
    }
  }
  __syncthreads();
  const double Dw = (double)fscal[4];
  double ls = 0.0;
  for (int b = t; b < BINS; b += 256) {
    unsigned c = (h[0][b] + h[1][b]) + (h[2][b] + h[3][b]);
    if (c) {
      atomicAdd(&bc[b], c);
      double pd = (double)c / Dw;
      ls -= pd * log2(pd);
    }
  }
  #pragma unroll
  for (int off = 32; off > 0; off >>= 1) ls += __shfl_down(ls, off);
  __shared__ double lsd[4];
  if (lane == 0) lsd[w] = ls;
  __syncthreads();
  if (t == 0) localent[row] = (lsd[0] + lsd[1]) + (lsd[2] + lsd[3]);
}

// ---------------- K4: batch entropy + per-row pf/keepf + fpart spot-check compare ----------------
__global__ __launch_bounds__(256) void k_final(const unsigned* __restrict__ bc,
    const float* __restrict__ fscal, const double* __restrict__ localent,
    const double* __restrict__ fpart, const double* __restrict__ dn,
    const double* __restrict__ chkpart, float* __restrict__ flg,
    float* __restrict__ pf, float* __restrict__ kf, int nq, int doChk) {
#pragma clang fp contract(off)
  const int t = threadIdx.x;
  if (doChk && t < 12) {   // compare spot-check entries vs fpart
    double s = 0.0;
    #pragma unroll
    for (int q = 0; q < 16; ++q) s += chkpart[t * 16 + q];
    double got = fpart[(size_t)CHK_TR[t] * 8 + CHK_SL[t]];
    if (fabs(got - s) > 2e-3 * fmax(fabs(s), 1e-30))
      atomicAdd(flg, 1e6f * (float)(t + 1));
  }
  const double Nw = (double)fscal[5];
  double be = 0.0;
  for (int b = t; b < BINS; b += 256) {
    unsigned c = bc[b];
    if (c) { double pd = (double)c / Nw; be -= pd * log2(pd); }
  }
  #pragma unroll
  for (int off = 32; off > 0; off >>= 1) be += __shfl_down(be, off);
  __shared__ double lsd[4];
  __shared__ double sbent;
  const int lane = t & 63, w = t >> 6;
  if (lane == 0) lsd[w] = be;
  __syncthreads();
  if (t == 0) sbent = (lsd[0] + lsd[1]) + (lsd[2] + lsd[3]);
  __syncthreads();
  const float bef = (float)sbent;
  for (int r = t; r < NROWS; r += 256) {
    double s = 0.0;
    for (int q = 0; q < nq; ++q) s += fpart[(size_t)r * nq + q];
    float f1f = (float)(s / (dn[r] * 1024.0));
    float lef = (float)localent[r];
    float f2f = lef / bef;
    if (f2f == 0.0f) { f1f = 0.0f; f2f = 1.0f; }
    else if (f2f < 1.0f) f2f = 1.0f / f2f;
    float keepf = f1f / f2f;
    pf[r] = 1.0f - keepf;
    kf[r] = keepf;
  }
}

// ---------------- K6: elementwise masked scale (float32 compare + division) ----------------
__global__ __launch_bounds__(256) void k_apply(const float* __restrict__ x,
    const float* __restrict__ u, const float* __restrict__ pf,
    const float* __restrict__ kf, const float* __restrict__ flg,
    float* __restrict__ out) {
#pragma clang fp contract(off)
  const size_t e = ((size_t)blockIdx.x * 256 + threadIdx.x) * 4;
  const float fl = flg[0];
  if (fl != 0.0f) {           // diagnostic mode: encode check code in out[0]
    float4 o = {0.f, 0.f, 0.f, 0.f};
    if (e == 0) o.x = fl;
    *(float4*)(out + e) = o;
    return;
  }
  const int row = (int)(e >> 14);
  const float pr = pf[row], kr = kf[row];
  const float4 xv = *(const float4*)(x + e);
  const float4 uv = *(const float4*)(u + e);
  float4 o;
  o.x = (uv.x > pr) ? (xv.x / kr) : 0.0f;
  o.y = (uv.y > pr) ? (xv.y / kr) : 0.0f;
  o.z = (uv.z > pr) ? (xv.z / kr) : 0.0f;
  o.w = (uv.w > pr) ? (xv.w / kr) : 0.0f;
  *(float4*)(out + e) = o;
}

extern "C" void kernel_launch(void* const* d_in, const int* in_sizes, int n_in,
                              void* d_out, int out_size, void* d_ws, size_t ws_size,
                              hipStream_t stream) {
  const float* x = (const float*)d_in[0];
  const float* u = (const float*)d_in[1];
  float* out = (float*)d_out;

  const size_t PLANE = (size_t)NROWS * DCOLS * sizeof(unsigned short);  // 32 MB
  const size_t NDBL  = 7 * 1024 + (size_t)NROWS * 16 + 192;             // stats + fpart + chkpart
  const size_t TAILB = NDBL * 8 + (2056 + 4) * 4 + BINS * 4;
  const bool big = ws_size >= 2 * PLANE + TAILB;

  char* base = (char*)d_ws;
  unsigned short* phi = (unsigned short*)base;
  unsigned short* plo = (unsigned short*)(base + PLANE);
  double* W = big ? (double*)(base + 2 * PLANE) : (double*)base;

  double* rowsum   = W;
  double* rowsumsq = W + 1024;
  double* rowmin   = W + 2048;
  double* rowmax   = W + 3072;
  double* m        = W + 4096;
  double* dn       = W + 5120;
  double* localent = W + 6144;
  double* fpart    = W + 7168;                        // 1024*16 doubles (big uses stride 8)
  double* chkpart  = W + 7168 + (size_t)NROWS * 16;   // 192 doubles
  float*  F        = (float*)(chkpart + 192);
  float*  pf       = F;
  float*  kf       = F + 1024;
  float*  fscal    = F + 2048;          // 8 floats
  float*  flg      = F + 2056;          // 4 floats
  unsigned* bc     = (unsigned*)(F + 2060);

  if (big) {
    float* Gs = out;                                   // 9.44M floats (0..37.7MB of out)
    unsigned* rowcnt = (unsigned*)(out + 10485760);    // 4MB at +40MB, disjoint from Gs
    k_rowsplit<<<NROWS, 256, 0, stream>>>(x, phi, plo, rowsum, rowsumsq, rowmin, rowmax);
    k_stats2<<<1, 256, 0, stream>>>(rowsum, rowsumsq, rowmin, rowmax, m, dn, fscal, flg, bc);
    k_gramm_sk<<<NPAIR2 * KSPL2, 256, 0, stream>>>(phi, plo, Gs);
    k_gepi_chk<<<NPAIR2 + 192, 256, 0, stream>>>(x, Gs, m, dn, fpart, chkpart, NPAIR2);
    k_hist_nc<<<NROWS, 256, 0, stream>>>(x, fscal, localent, rowcnt);
    k_bsum<<<BINS / 8, 256, 0, stream>>>(rowcnt, bc);
    k_final<<<1, 256, 0, stream>>>(bc, fscal, localent, fpart, dn, chkpart, flg, pf, kf, 8, 1);
  } else {
    k_rowstats<<<NROWS, 256, 0, stream>>>(x, rowsum, rowsumsq, rowmin, rowmax);
    k_stats2<<<1, 256, 0, stream>>>(rowsum, rowsumsq, rowmin, rowmax, m, dn, fscal, flg, bc);
    k_gram<<<dim3(16, 16), 256, 0, stream>>>(x, m, dn, fpart);
    k_hist<<<NROWS, 256, 0, stream>>>(x, fscal, localent, bc);
    k_final<<<1, 256, 0, stream>>>(bc, fscal, localent, fpart, dn, chkpart, flg, pf, kf, 16, 0);
  }
  k_apply<<<NTOT / (256 * 4), 256, 0, stream>>>(x, u, pf, kf, flg, out);
}